// Round 7
// baseline (275.231 us; speedup 1.0000x reference)
//
#include <hip/hip_runtime.h>
#include <cstdint>
#include <cstddef>

// Problem constants (B=2, S=2048, D=1024, H=16, hd=64)
#define NH   16
#define SEQ  2048
#define DM   1024
#define HD   64
#define KDIM 1024
#define MROWS 4096  // B*S
#define CH   2      // KV chunks per q-tile (attention split)

using short8  = __attribute__((ext_vector_type(8))) short;
using short4v = __attribute__((ext_vector_type(4))) short;
using floatx4 = __attribute__((ext_vector_type(4))) float;

// fp32 -> bf16 round-to-nearest-even (bit pattern in a short)
__device__ __forceinline__ short f2bf(float f) {
  unsigned int u = __float_as_uint(f);
  u += 0x7fffu + ((u >> 16) & 1u);
  return (short)(u >> 16);
}
__device__ __forceinline__ float bf2f(short s) {
  return __uint_as_float(((unsigned int)(unsigned short)s) << 16);
}
// truncating pack of two fp32 -> bf16x2 in one v_perm_b32 (lo in low 16)
__device__ __forceinline__ unsigned int pktrunc(float lo, float hi) {
  return __builtin_amdgcn_perm(__float_as_uint(hi), __float_as_uint(lo),
                               0x07060302u);
}

__device__ __forceinline__ void async_ld16(const void* g, void* l) {
  __builtin_amdgcn_global_load_lds(
      (const __attribute__((address_space(1))) void*)g,
      (__attribute__((address_space(3))) void*)l, 16, 0, 0);
}

// ------------------------------------------- convert + RoPE table precompute -
struct Cvt8 {
  const float* src[8];
  void* dst[8];
  int n[8];
  const int* pos[8];
};

__global__ void convert8(Cvt8 a) {
  const int which = blockIdx.y;
  const int stride = gridDim.x * blockDim.x;
  if (which < 6) {
    const float4* s = (const float4*)a.src[which];
    short4v* d = (short4v*)a.dst[which];
    const int n4 = a.n[which] >> 2;
    for (int i = blockIdx.x * blockDim.x + threadIdx.x; i < n4; i += stride) {
      float4 v = s[i];
      short4v o;
      o.x = f2bf(v.x); o.y = f2bf(v.y); o.z = f2bf(v.z); o.w = f2bf(v.w);
      d[i] = o;
    }
  } else {
    const int* pos = a.pos[which];
    float2* d = (float2*)a.dst[which];
    const int n = a.n[which];
    for (int i = blockIdx.x * blockDim.x + threadIdx.x; i < n; i += stride) {
      int s = i >> 5, d1 = i & 31;
      float fr = __powf(10000.f, -(float)d1 * (1.f / 32.f));
      float ang = (float)pos[s] * fr;
      float sn, cs;
      __sincosf(ang, &sn, &cs);
      d[i] = make_float2(cs, sn);
    }
  }
}

// ------------------------------------------------------------- GEMM core ----
// C[128x128] = A[128 of MxK] * B[128 of NxK]^T.
// BK=32, double-buffered LDS, ONE barrier per iter: stage(next) is issued
// before compute(cur); the compiler's vmcnt(0) drain before s_barrier then
// lands after compute, hiding the staging latency. XOR chunk swizzle keeps
// b128 frag reads 2-way (free).
__device__ __forceinline__ void gemm_core(const short* __restrict__ A,
                                          const short* __restrict__ B,
                                          int row0, int col0,
                                          short* As, short* Bs,
                                          floatx4 (&acc)[4][4], int tid) {
  const int lane = tid & 63;
  const int w = tid >> 6;
  const int quad = lane >> 4;
  const int ln = lane & 15;
  const int wr = w >> 1, wc = w & 1;
  const int swz = (quad ^ ((ln >> 1) & 3)) * 8;

#pragma unroll
  for (int i = 0; i < 4; ++i)
#pragma unroll
    for (int j = 0; j < 4; ++j) acc[i][j] = (floatx4){0.f, 0.f, 0.f, 0.f};

  auto stage = [&](int k0, int buf) {
#pragma unroll
    for (int g = 0; g < 2; ++g) {
      int slot = g * 256 + tid;               // 0..511
      int row = slot >> 2;
      int grp = (slot & 3) ^ ((slot >> 3) & 3);
      int src = k0 + grp * 8;
      async_ld16(A + (size_t)(row0 + row) * KDIM + src, As + buf * 4096 + slot * 8);
      async_ld16(B + (size_t)(col0 + row) * KDIM + src, Bs + buf * 4096 + slot * 8);
    }
  };

  stage(0, 0);
  __syncthreads();
  int cur = 0;
  for (int k0 = 0; k0 < KDIM; k0 += 32) {
    if (k0 + 32 < KDIM) stage(k0 + 32, cur ^ 1);
    const short* Ab = As + cur * 4096;
    const short* Bb = Bs + cur * 4096;
    short8 af[4], bfr[4];
#pragma unroll
    for (int i = 0; i < 4; ++i)
      af[i] = *(const short8*)(Ab + (wr * 64 + i * 16 + ln) * 32 + swz);
#pragma unroll
    for (int j = 0; j < 4; ++j)
      bfr[j] = *(const short8*)(Bb + (wc * 64 + j * 16 + ln) * 32 + swz);
#pragma unroll
    for (int i = 0; i < 4; ++i)
#pragma unroll
      for (int j = 0; j < 4; ++j)
        acc[i][j] = __builtin_amdgcn_mfma_f32_16x16x32_bf16(af[i], bfr[j], acc[i][j], 0, 0, 0);
    __syncthreads();
    cur ^= 1;
  }
}

// -------------------------------------------------- fused QKV proj + RoPE ---
__global__ __launch_bounds__(256) void proj_gemm(
    const short* __restrict__ qxb, const short* __restrict__ kvxb,
    const short* __restrict__ Wqb, const short* __restrict__ Wkb,
    const short* __restrict__ Wvb,
    const float* __restrict__ bq, const float* __restrict__ bv,
    short* __restrict__ Qo, short* __restrict__ Ko, short* __restrict__ Vt,
    const float2* __restrict__ qtab, const float2* __restrict__ ktab) {
  __shared__ __align__(16) short As[2 * 4096];
  __shared__ __align__(16) short Bs[2 * 4096];

  const int tid = threadIdx.x;
  const int lane = tid & 63;
  const int w = tid >> 6;
  const int quad = lane >> 4;
  const int ln = lane & 15;
  const int wr = w >> 1, wc = w & 1;
  const int z = blockIdx.z;

  int row0, col0;
  const short *A, *B;
  if (z == 2) {  // swapped: A=Wv, B=kvx -> C = V^T tile
    A = Wvb; B = kvxb;
    row0 = blockIdx.x * 128;   // d-dim (1024)
    col0 = blockIdx.y * 128;   // s-dim (4096)
  } else {
    A = z ? kvxb : qxb;
    B = z ? Wkb : Wqb;
    row0 = blockIdx.y * 128;
    col0 = blockIdx.x * 128;
  }

  floatx4 acc[4][4];
  gemm_core(A, B, row0, col0, As, Bs, acc, tid);

  if (z == 2) {
#pragma unroll
    for (int i = 0; i < 4; ++i)
#pragma unroll
      for (int r = 0; r < 4; ++r) {
        int nr = row0 + wr * 64 + i * 16 + quad * 4 + r;  // (h,d)
        int h = nr >> 6, d = nr & 63;
        float bb = bv[nr];
        size_t base = ((size_t)(h)*HD + d) * SEQ;
#pragma unroll
        for (int j = 0; j < 4; ++j) {
          int sc = col0 + wc * 64 + j * 16 + ln;  // (b,s)
          int b = sc >> 11, s = sc & (SEQ - 1);
          Vt[((size_t)b * NH * HD) * SEQ + base + s] = f2bf(acc[i][j][r] + bb);
        }
      }
  } else {
    const int colbase = col0 + wc * 64;
    const float scale = (z == 0) ? 0.125f : 1.0f;
    const float* bias = (z == 0) ? bq : nullptr;
    const float2* tab = (z == 0) ? qtab : ktab;
    short* Out = (z == 0) ? Qo : Ko;
#pragma unroll
    for (int j = 0; j < 2; ++j) {
      int col1 = colbase + j * 16 + ln;
      float b1 = bias ? bias[col1] : 0.f;
      float b2 = bias ? bias[col1 + 32] : 0.f;
      int h = col1 >> 6;
      int d1 = col1 & 63;
#pragma unroll
      for (int i = 0; i < 4; ++i)
#pragma unroll
        for (int r = 0; r < 4; ++r) {
          int row = row0 + wr * 64 + i * 16 + quad * 4 + r;
          int b = row >> 11, s = row & (SEQ - 1);
          float2 cs_sn = tab[s * 32 + d1];
          float x1 = acc[i][j][r] + b1;
          float x2 = acc[i][j + 2][r] + b2;
          float o1 = (x1 * cs_sn.x - x2 * cs_sn.y) * scale;
          float o2 = (x2 * cs_sn.x + x1 * cs_sn.y) * scale;
          size_t basq = ((((size_t)b * NH + h) * SEQ) + s) * HD;
          Out[basq + d1] = f2bf(o1);
          Out[basq + d1 + 32] = f2bf(o2);
        }
    }
  }
}

// --------------------------------------------------------- out projection ---
// 64x128 tiles -> 512 blocks. BK=32 dbuf, 1 barrier/iter.
__global__ __launch_bounds__(256) void out_gemm(
    const short* __restrict__ Ab, const short* __restrict__ Bb,
    const float* __restrict__ bias, float* __restrict__ out) {
  __shared__ __align__(16) short As[2 * 2048];
  __shared__ __align__(16) short Bs[2 * 4096];
  const int tid = threadIdx.x;
  const int lane = tid & 63;
  const int w = tid >> 6;
  const int quad = lane >> 4;
  const int ln = lane & 15;
  const int wr = w >> 1, wc = w & 1;
  const int swz = (quad ^ ((ln >> 1) & 3)) * 8;
  const int row0 = (blockIdx.x >> 3) * 64;   // M=4096 -> 64 tiles
  const int col0 = (blockIdx.x & 7) * 128;   // N=1024 -> 8 tiles

  floatx4 acc[2][4];
#pragma unroll
  for (int i = 0; i < 2; ++i)
#pragma unroll
    for (int j = 0; j < 4; ++j) acc[i][j] = (floatx4){0.f, 0.f, 0.f, 0.f};

  auto stage = [&](int k0, int buf) {
    {  // A: 256 slots, 1/thread
      int slot = tid;
      int row = slot >> 2;
      int grp = (slot & 3) ^ ((slot >> 3) & 3);
      async_ld16(Ab + (size_t)(row0 + row) * KDIM + k0 + grp * 8,
                 As + buf * 2048 + slot * 8);
    }
#pragma unroll
    for (int g = 0; g < 2; ++g) {  // B: 512 slots
      int slot = g * 256 + tid;
      int row = slot >> 2;
      int grp = (slot & 3) ^ ((slot >> 3) & 3);
      async_ld16(Bb + (size_t)(col0 + row) * KDIM + k0 + grp * 8,
                 Bs + buf * 4096 + slot * 8);
    }
  };

  stage(0, 0);
  __syncthreads();
  int cur = 0;
  for (int k0 = 0; k0 < KDIM; k0 += 32) {
    if (k0 + 32 < KDIM) stage(k0 + 32, cur ^ 1);
    const short* Ac = As + cur * 2048;
    const short* Bc = Bs + cur * 4096;
    short8 af[2], bfr[4];
#pragma unroll
    for (int i = 0; i < 2; ++i)
      af[i] = *(const short8*)(Ac + (wr * 32 + i * 16 + ln) * 32 + swz);
#pragma unroll
    for (int j = 0; j < 4; ++j)
      bfr[j] = *(const short8*)(Bc + (wc * 64 + j * 16 + ln) * 32 + swz);
#pragma unroll
    for (int i = 0; i < 2; ++i)
#pragma unroll
      for (int j = 0; j < 4; ++j)
        acc[i][j] = __builtin_amdgcn_mfma_f32_16x16x32_bf16(af[i], bfr[j], acc[i][j], 0, 0, 0);
    __syncthreads();
    cur ^= 1;
  }

#pragma unroll
  for (int j = 0; j < 4; ++j) {
    int col = col0 + wc * 64 + j * 16 + ln;
    float bb = bias[col];
#pragma unroll
    for (int i = 0; i < 2; ++i)
#pragma unroll
      for (int r = 0; r < 4; ++r) {
        int row = row0 + wr * 32 + i * 16 + quad * 4 + r;
        out[(size_t)row * DM + col] = acc[i][j][r] + bb;
      }
  }
}

// ----------------------------------------------- flash attention, KV-split --
// 128-row q-tiles: 4 waves x 32 q-rows. CH=2 parity chunks over 64-wide KV
// strips. Double-buffered K/V staging, ONE barrier per strip. S^T = K*Q^T;
// P truncation-packed; swizzled LDS tiles; longest q-tiles dispatch first.
__global__ __launch_bounds__(256) void attn_partial(
    const short* __restrict__ Q, const short* __restrict__ Kc,
    const short* __restrict__ Vtg, short* __restrict__ Po,
    float* __restrict__ Lo) {
  const int tid = threadIdx.x;
  const int lane = tid & 63;
  const int w = tid >> 6;       // 0..3
  const int quad = lane >> 4;
  const int ln = lane & 15;
  const int swz = (quad ^ ((ln >> 1) & 3)) * 8;
  const int bh = blockIdx.y;
  const int bx = blockIdx.x;    // 0..31
  const int QT = 15 - (bx >> 1);  // longest first
  const int ch = bx & 1;

  const int q0 = QT * 128;
  const int wlo = q0 + w * 32;

  const short* Qb = Q + (size_t)bh * SEQ * HD;
  const short* Kb = Kc + (size_t)bh * SEQ * HD;
  const short* Vb = Vtg + (size_t)bh * HD * SEQ;

  __shared__ __align__(16) short Ks[2 * 4096];     // dbuf [kk(d-half)][s'][32]
  __shared__ __align__(16) short Vs[2 * 4096];     // dbuf [kk(s'-half)][d][32]
  __shared__ __align__(16) short Pt[4][32 * 72];   // per-wave P^T round-trip

  short8 qa[2][2];
#pragma unroll
  for (int i = 0; i < 2; ++i)
#pragma unroll
    for (int kk = 0; kk < 2; ++kk)
      qa[i][kk] = *(const short8*)(Qb + (size_t)(wlo + i * 16 + ln) * HD +
                                   quad * 8 + kk * 32);

  floatx4 oacc[4][2];
  float lp[2];
#pragma unroll
  for (int jd = 0; jd < 4; ++jd)
#pragma unroll
    for (int i = 0; i < 2; ++i) oacc[jd][i] = (floatx4){0.f, 0.f, 0.f, 0.f};
  lp[0] = lp[1] = 0.f;

  auto stage = [&](int t, int buf) {
#pragma unroll
    for (int g = 0; g < 2; ++g) {
      int slot = (w * 2 + g) * 64 + lane;  // 0..511
      int kk = slot >> 8;
      int rowi = (slot >> 2) & 63;
      int grp = (slot & 3) ^ ((slot >> 3) & 3);
      async_ld16(Kb + (size_t)(t + rowi) * HD + kk * 32 + grp * 8,
                 Ks + buf * 4096 + slot * 8);
      async_ld16(Vb + (size_t)rowi * SEQ + t + kk * 32 + grp * 8,
                 Vs + buf * 4096 + slot * 8);
    }
  };

  const int t_end = q0 + 128;
  const int t0 = ch * 64;
  stage(t0, 0);
  __syncthreads();
  int cur = 0;
  for (int t = t0; t < t_end; t += CH * 64) {
    if (t + CH * 64 < t_end) stage(t + CH * 64, cur ^ 1);

    if (t <= wlo + 31) {
      const short* Kcur = Ks + cur * 4096;
      const short* Vcur = Vs + cur * 4096;
      // S^T = K * Q^T
      floatx4 sacc[4][2];
#pragma unroll
      for (int c = 0; c < 4; ++c)
#pragma unroll
        for (int i = 0; i < 2; ++i) sacc[c][i] = (floatx4){0.f, 0.f, 0.f, 0.f};
#pragma unroll
      for (int kk = 0; kk < 2; ++kk)
#pragma unroll
        for (int c = 0; c < 4; ++c) {
          short8 kb = *(const short8*)(Kcur + kk * 2048 + (c * 16 + ln) * 32 + swz);
          sacc[c][0] = __builtin_amdgcn_mfma_f32_16x16x32_bf16(kb, qa[0][kk], sacc[c][0], 0, 0, 0);
          sacc[c][1] = __builtin_amdgcn_mfma_f32_16x16x32_bf16(kb, qa[1][kk], sacc[c][1], 0, 0, 0);
        }

      // exp (no max), mask on partial tiles, truncating bf16 pack
      const bool dmask = (t + 63 > wlo);
#pragma unroll
      for (int c = 0; c < 4; ++c)
#pragma unroll
        for (int i = 0; i < 2; ++i) {
          float p[4];
#pragma unroll
          for (int r = 0; r < 4; ++r) {
            float pv = __expf(sacc[c][i][r]);
            if (dmask) {
              int sp = t + c * 16 + quad * 4 + r;
              int qq = wlo + i * 16 + ln;
              if (sp > qq) pv = 0.f;
            }
            lp[i] += pv;
            p[r] = pv;
          }
          uint2 uu;
          uu.x = pktrunc(p[0], p[1]);
          uu.y = pktrunc(p[2], p[3]);
          *(uint2*)(&Pt[w][(i * 16 + ln) * 72 + c * 16 + quad * 4]) = uu;
        }
      // Pt wave-private; lgkmcnt orders write->read

      // O^T += V^T * P^T
#pragma unroll
      for (int kk = 0; kk < 2; ++kk) {
        short8 pb0 = *(const short8*)(&Pt[w][(ln) * 72 + kk * 32 + quad * 8]);
        short8 pb1 = *(const short8*)(&Pt[w][(16 + ln) * 72 + kk * 32 + quad * 8]);
#pragma unroll
        for (int jd = 0; jd < 4; ++jd) {
          short8 va = *(const short8*)(Vcur + kk * 2048 + (jd * 16 + ln) * 32 + swz);
          oacc[jd][0] = __builtin_amdgcn_mfma_f32_16x16x32_bf16(va, pb0, oacc[jd][0], 0, 0, 0);
          oacc[jd][1] = __builtin_amdgcn_mfma_f32_16x16x32_bf16(va, pb1, oacc[jd][1], 0, 0, 0);
        }
      }
    }
    __syncthreads();  // drains next-strip staging; syncs LDS reads of cur
    cur ^= 1;
  }

  // store partials: per (bh,QT,ch): 128 q x 64 d bf16 + 128 l fp32
  const size_t idx = ((size_t)bh * 16 + QT) * CH + ch;
  short* Pob = Po + idx * 8192;
#pragma unroll
  for (int jd = 0; jd < 4; ++jd)
#pragma unroll
    for (int i = 0; i < 2; ++i) {
      short4v pk;
#pragma unroll
      for (int r = 0; r < 4; ++r) pk[r] = f2bf(oacc[jd][i][r]);
      *(short4v*)(Pob + (w * 32 + i * 16 + ln) * 64 + jd * 16 + quad * 4) = pk;
    }
#pragma unroll
  for (int i = 0; i < 2; ++i) {
    float l = lp[i];
    l += __shfl_xor(l, 16, 64);
    l += __shfl_xor(l, 32, 64);
    if (quad == 0) Lo[idx * 128 + w * 32 + i * 16 + ln] = l;
  }
}

// --------------------------------------------------- combine KV-split parts -
__global__ __launch_bounds__(256) void attn_reduce(
    const short* __restrict__ Po, const float* __restrict__ Lo,
    short* __restrict__ Ov) {
  const int bh = blockIdx.y;
  const int b = bh >> 4, h = bh & 15;
  const int tid = threadIdx.x;
  const int s = blockIdx.x * 64 + (tid >> 2);   // 0..2047
  const int d0 = (tid & 3) * 16;
  const int QT = s >> 7, ql = s & 127;
  const size_t i0 = ((size_t)bh * 16 + QT) * CH;

  float l = Lo[i0 * 128 + ql] + Lo[(i0 + 1) * 128 + ql];
  const short8* p0 = (const short8*)(Po + i0 * 8192 + ql * 64 + d0);
  const short8* p1 = (const short8*)(Po + (i0 + 1) * 8192 + ql * 64 + d0);
  short8 a0 = p0[0], a1 = p0[1], c0 = p1[0], c1 = p1[1];
  float inv = 1.f / l;
  short8 o0, o1;
#pragma unroll
  for (int e = 0; e < 8; ++e) {
    o0[e] = f2bf((bf2f(a0[e]) + bf2f(c0[e])) * inv);
    o1[e] = f2bf((bf2f(a1[e]) + bf2f(c1[e])) * inv);
  }
  short* dst = Ov + ((size_t)b * SEQ + s) * DM + h * HD + d0;
  *(short8*)dst = o0;
  *((short8*)dst + 1) = o1;
}

// ------------------------------------------------------------------ launch --
extern "C" void kernel_launch(void* const* d_in, const int* in_sizes, int n_in,
                              void* d_out, int out_size, void* d_ws, size_t ws_size,
                              hipStream_t stream) {
  const float* qx  = (const float*)d_in[0];
  const float* kvx = (const float*)d_in[1];
  const float* Wq = (const float*)d_in[4];
  const float* bq = (const float*)d_in[5];
  const float* Wk = (const float*)d_in[6];
  const float* Wv = (const float*)d_in[7];
  const float* bv = (const float*)d_in[8];
  const float* Wo = (const float*)d_in[9];
  const float* bo = (const float*)d_in[10];
  const int* qpos  = (const int*)d_in[11];
  const int* kvpos = (const int*)d_in[12];

  char* ws = (char*)d_ws;
  short* qxb  = (short*)(ws + 0);
  short* kvxb = (short*)(ws + 8388608);
  short* Wqb  = (short*)(ws + 16777216);
  short* Wkb  = (short*)(ws + 18874368);
  short* Wvb  = (short*)(ws + 20971520);
  short* Wob  = (short*)(ws + 23068672);
  short* Qbf  = (short*)(ws + 25165824);
  short* Kbf  = (short*)(ws + 33554432);
  short* Vtb  = (short*)(ws + 41943040);
  short* WVbf = (short*)(ws + 50331648);
  float2* qtab = (float2*)(ws + 50331648);
  float2* ktab = (float2*)(ws + 50331648 + 524288);
  short* Po = (short*)(ws + 0);          // 32*16*CH*8192 bf16 = 16 MB
  float* Lo = (float*)(ws + 16777216);   // 32*16*CH*128 fp32 = 512 KB

  Cvt8 c;
  c.src[0] = qx;  c.dst[0] = qxb;  c.n[0] = MROWS * KDIM; c.pos[0] = nullptr;
  c.src[1] = kvx; c.dst[1] = kvxb; c.n[1] = MROWS * KDIM; c.pos[1] = nullptr;
  c.src[2] = Wq;  c.dst[2] = Wqb;  c.n[2] = DM * KDIM;    c.pos[2] = nullptr;
  c.src[3] = Wk;  c.dst[3] = Wkb;  c.n[3] = DM * KDIM;    c.pos[3] = nullptr;
  c.src[4] = Wv;  c.dst[4] = Wvb;  c.n[4] = DM * KDIM;    c.pos[4] = nullptr;
  c.src[5] = Wo;  c.dst[5] = Wob;  c.n[5] = DM * KDIM;    c.pos[5] = nullptr;
  c.src[6] = nullptr; c.dst[6] = qtab; c.n[6] = SEQ * 32; c.pos[6] = qpos;
  c.src[7] = nullptr; c.dst[7] = ktab; c.n[7] = SEQ * 32; c.pos[7] = kvpos;
  convert8<<<dim3(1024, 8), 256, 0, stream>>>(c);

  proj_gemm<<<dim3(DM / 128, MROWS / 128, 3), 256, 0, stream>>>(
      qxb, kvxb, Wqb, Wkb, Wvb, bq, bv, Qbf, Kbf, Vtb, qtab, ktab);

  attn_partial<<<dim3(16 * CH, 2 * NH), 256, 0, stream>>>(Qbf, Kbf, Vtb, Po, Lo);

  attn_reduce<<<dim3(SEQ / 64, 2 * NH), 256, 0, stream>>>(Po, Lo, WVbf);

  out_gemm<<<dim3(64 * 8), 256, 0, stream>>>(WVbf, Wob, bo, (float*)d_out);
}

// Round 8
// 253.409 us; speedup vs baseline: 1.0861x; 1.0861x over previous
//
#include <hip/hip_runtime.h>
#include <cstdint>
#include <cstddef>

// Problem constants (B=2, S=2048, D=1024, H=16, hd=64)
#define NH   16
#define SEQ  2048
#define DM   1024
#define HD   64
#define KDIM 1024
#define MROWS 4096  // B*S
#define CH   2      // KV chunks per q-tile (attention split)

using short8  = __attribute__((ext_vector_type(8))) short;
using short4v = __attribute__((ext_vector_type(4))) short;
using floatx4 = __attribute__((ext_vector_type(4))) float;

// fp32 -> bf16 round-to-nearest-even (bit pattern in a short)
__device__ __forceinline__ short f2bf(float f) {
  unsigned int u = __float_as_uint(f);
  u += 0x7fffu + ((u >> 16) & 1u);
  return (short)(u >> 16);
}
__device__ __forceinline__ float bf2f(short s) {
  return __uint_as_float(((unsigned int)(unsigned short)s) << 16);
}
// truncating pack of two fp32 -> bf16x2 in one v_perm_b32 (lo in low 16)
__device__ __forceinline__ unsigned int pktrunc(float lo, float hi) {
  return __builtin_amdgcn_perm(__float_as_uint(hi), __float_as_uint(lo),
                               0x07060302u);
}

__device__ __forceinline__ void async_ld16(const void* g, void* l) {
  __builtin_amdgcn_global_load_lds(
      (const __attribute__((address_space(1))) void*)g,
      (__attribute__((address_space(3))) void*)l, 16, 0, 0);
}

// ------------------------------------------- convert + RoPE table precompute -
struct Cvt8 {
  const float* src[8];
  void* dst[8];
  int n[8];
  const int* pos[8];
};

__global__ void convert8(Cvt8 a) {
  const int which = blockIdx.y;
  const int stride = gridDim.x * blockDim.x;
  if (which < 6) {
    const float4* s = (const float4*)a.src[which];
    short4v* d = (short4v*)a.dst[which];
    const int n4 = a.n[which] >> 2;
    for (int i = blockIdx.x * blockDim.x + threadIdx.x; i < n4; i += stride) {
      float4 v = s[i];
      short4v o;
      o.x = f2bf(v.x); o.y = f2bf(v.y); o.z = f2bf(v.z); o.w = f2bf(v.w);
      d[i] = o;
    }
  } else {
    const int* pos = a.pos[which];
    float2* d = (float2*)a.dst[which];
    const int n = a.n[which];
    for (int i = blockIdx.x * blockDim.x + threadIdx.x; i < n; i += stride) {
      int s = i >> 5, d1 = i & 31;
      float fr = __powf(10000.f, -(float)d1 * (1.f / 32.f));
      float ang = (float)pos[s] * fr;
      float sn, cs;
      __sincosf(ang, &sn, &cs);
      d[i] = make_float2(cs, sn);
    }
  }
}

// ------------------------------------------------------------- GEMM core ----
// C[128x128] = A[128 of MxK] * B[128 of NxK]^T, BK=64, single-buffered,
// layout [kk][row][32] with XOR chunk swizzle (b128 frag reads 2-way = free).
__device__ __forceinline__ void gemm_core(const short* __restrict__ A,
                                          const short* __restrict__ B,
                                          int row0, int col0,
                                          short* As, short* Bs,
                                          floatx4 (&acc)[4][4], int tid) {
  const int lane = tid & 63;
  const int w = tid >> 6;
  const int quad = lane >> 4;
  const int ln = lane & 15;
  const int wr = w >> 1, wc = w & 1;
  const int swz = (quad ^ ((ln >> 1) & 3)) * 8;

#pragma unroll
  for (int i = 0; i < 4; ++i)
#pragma unroll
    for (int j = 0; j < 4; ++j) acc[i][j] = (floatx4){0.f, 0.f, 0.f, 0.f};

  for (int k0 = 0; k0 < KDIM; k0 += 64) {
    __syncthreads();
#pragma unroll
    for (int g = 0; g < 4; ++g) {
      int slot = g * 256 + tid;               // 0..1023
      int kk = slot >> 9;
      int row = (slot >> 2) & 127;
      int grp = (slot & 3) ^ ((slot >> 3) & 3);   // swizzle source chunk
      int src = k0 + kk * 32 + grp * 8;
      async_ld16(A + (size_t)(row0 + row) * KDIM + src, As + slot * 8);
      async_ld16(B + (size_t)(col0 + row) * KDIM + src, Bs + slot * 8);
    }
    __syncthreads();

#pragma unroll
    for (int ks = 0; ks < 2; ++ks) {
      short8 af[4], bfr[4];
#pragma unroll
      for (int i = 0; i < 4; ++i)
        af[i] = *(const short8*)(As + ks * 4096 + (wr * 64 + i * 16 + ln) * 32 + swz);
#pragma unroll
      for (int j = 0; j < 4; ++j)
        bfr[j] = *(const short8*)(Bs + ks * 4096 + (wc * 64 + j * 16 + ln) * 32 + swz);
#pragma unroll
      for (int i = 0; i < 4; ++i)
#pragma unroll
        for (int j = 0; j < 4; ++j)
          acc[i][j] = __builtin_amdgcn_mfma_f32_16x16x32_bf16(af[i], bfr[j], acc[i][j], 0, 0, 0);
    }
  }
}

// -------------------------------------------------- fused QKV proj + RoPE ---
__global__ __launch_bounds__(256) void proj_gemm(
    const short* __restrict__ qxb, const short* __restrict__ kvxb,
    const short* __restrict__ Wqb, const short* __restrict__ Wkb,
    const short* __restrict__ Wvb,
    const float* __restrict__ bq, const float* __restrict__ bv,
    short* __restrict__ Qo, short* __restrict__ Ko, short* __restrict__ Vt,
    const float2* __restrict__ qtab, const float2* __restrict__ ktab) {
  __shared__ __align__(16) short As[128 * 64];
  __shared__ __align__(16) short Bs[128 * 64];

  const int tid = threadIdx.x;
  const int lane = tid & 63;
  const int w = tid >> 6;
  const int quad = lane >> 4;
  const int ln = lane & 15;
  const int wr = w >> 1, wc = w & 1;
  const int z = blockIdx.z;

  int row0, col0;
  const short *A, *B;
  if (z == 2) {  // swapped: A=Wv, B=kvx -> C = V^T tile
    A = Wvb; B = kvxb;
    row0 = blockIdx.x * 128;   // d-dim (1024)
    col0 = blockIdx.y * 128;   // s-dim (4096)
  } else {
    A = z ? kvxb : qxb;
    B = z ? Wkb : Wqb;
    row0 = blockIdx.y * 128;
    col0 = blockIdx.x * 128;
  }

  floatx4 acc[4][4];
  gemm_core(A, B, row0, col0, As, Bs, acc, tid);

  if (z == 2) {
#pragma unroll
    for (int i = 0; i < 4; ++i)
#pragma unroll
      for (int r = 0; r < 4; ++r) {
        int nr = row0 + wr * 64 + i * 16 + quad * 4 + r;  // (h,d)
        int h = nr >> 6, d = nr & 63;
        float bb = bv[nr];
        size_t base = ((size_t)(h)*HD + d) * SEQ;
#pragma unroll
        for (int j = 0; j < 4; ++j) {
          int sc = col0 + wc * 64 + j * 16 + ln;  // (b,s)
          int b = sc >> 11, s = sc & (SEQ - 1);
          Vt[((size_t)b * NH * HD) * SEQ + base + s] = f2bf(acc[i][j][r] + bb);
        }
      }
  } else {
    const int colbase = col0 + wc * 64;
    const float scale = (z == 0) ? 0.125f : 1.0f;
    const float* bias = (z == 0) ? bq : nullptr;
    const float2* tab = (z == 0) ? qtab : ktab;
    short* Out = (z == 0) ? Qo : Ko;
#pragma unroll
    for (int j = 0; j < 2; ++j) {
      int col1 = colbase + j * 16 + ln;
      float b1 = bias ? bias[col1] : 0.f;
      float b2 = bias ? bias[col1 + 32] : 0.f;
      int h = col1 >> 6;
      int d1 = col1 & 63;
#pragma unroll
      for (int i = 0; i < 4; ++i)
#pragma unroll
        for (int r = 0; r < 4; ++r) {
          int row = row0 + wr * 64 + i * 16 + quad * 4 + r;
          int b = row >> 11, s = row & (SEQ - 1);
          float2 cs_sn = tab[s * 32 + d1];
          float x1 = acc[i][j][r] + b1;
          float x2 = acc[i][j + 2][r] + b2;
          float o1 = (x1 * cs_sn.x - x2 * cs_sn.y) * scale;
          float o2 = (x2 * cs_sn.x + x1 * cs_sn.y) * scale;
          size_t basq = ((((size_t)b * NH + h) * SEQ) + s) * HD;
          Out[basq + d1] = f2bf(o1);
          Out[basq + d1 + 32] = f2bf(o2);
        }
    }
  }
}

// -------------------------- out projection with fused attention combine -----
// A[s][k=h*64+d] = (Po[ch0]+Po[ch1]) / (Lo[ch0]+Lo[ch1]); BK=64 = one head,
// so normalization folds into A-staging. 64x128 tiles -> 512 blocks.
__global__ __launch_bounds__(256) void out_gemm(
    const short* __restrict__ Po, const float* __restrict__ Lo,
    const short* __restrict__ Bb,
    const float* __restrict__ bias, float* __restrict__ out) {
  __shared__ __align__(16) short As[64 * 64];
  __shared__ __align__(16) short Bs[128 * 64];
  const int tid = threadIdx.x;
  const int lane = tid & 63;
  const int w = tid >> 6;
  const int quad = lane >> 4;
  const int ln = lane & 15;
  const int wr = w >> 1, wc = w & 1;
  const int swz = (quad ^ ((ln >> 1) & 3)) * 8;
  const int row0 = (blockIdx.x >> 3) * 64;   // M=4096 -> 64 tiles (s-dim)
  const int col0 = (blockIdx.x & 7) * 128;   // N=1024 -> 8 tiles
  const int b16 = (row0 >> 11) * 16;         // b * NH
  const int qt = (row0 & (SEQ - 1)) >> 6;    // 64-row q-tile index

  floatx4 acc[2][4];
#pragma unroll
  for (int i = 0; i < 2; ++i)
#pragma unroll
    for (int j = 0; j < 4; ++j) acc[i][j] = (floatx4){0.f, 0.f, 0.f, 0.f};

  for (int k0 = 0; k0 < KDIM; k0 += 64) {
    __syncthreads();
    {
      // A: combine KV-split partials + normalize + pack, 512 slots (2/thread)
      const int h = k0 >> 6;
      const size_t ib = ((size_t)(b16 + h) * 32 + qt) * CH;
      const short* P0 = Po + (ib + 0) * 4096;
      const short* P1 = Po + (ib + 1) * 4096;
      const float* L0 = Lo + (ib + 0) * 64;
      const float* L1 = Lo + (ib + 1) * 64;
#pragma unroll
      for (int g = 0; g < 2; ++g) {
        int slot = g * 256 + tid;             // 0..511
        int kk = slot >> 8;
        int row = (slot >> 2) & 63;
        int grp = (slot & 3) ^ ((slot >> 3) & 3);
        int off = row * 64 + kk * 32 + grp * 8;
        short8 a0 = *(const short8*)(P0 + off);
        short8 a1 = *(const short8*)(P1 + off);
        float inv = 1.f / (L0[row] + L1[row]);
        float v[8];
#pragma unroll
        for (int e = 0; e < 8; ++e) v[e] = (bf2f(a0[e]) + bf2f(a1[e])) * inv;
        uint4 u;
        u.x = pktrunc(v[0], v[1]);
        u.y = pktrunc(v[2], v[3]);
        u.z = pktrunc(v[4], v[5]);
        u.w = pktrunc(v[6], v[7]);
        *(uint4*)(As + slot * 8) = u;
      }
      // B: async staging of Wo rows (k-contig), 1024 slots (4/thread)
#pragma unroll
      for (int g = 0; g < 4; ++g) {
        int slot = g * 256 + tid;             // 0..1023
        int kk = slot >> 9;
        int row = (slot >> 2) & 127;
        int grp = (slot & 3) ^ ((slot >> 3) & 3);
        async_ld16(Bb + (size_t)(col0 + row) * KDIM + k0 + kk * 32 + grp * 8,
                   Bs + slot * 8);
      }
    }
    __syncthreads();

#pragma unroll
    for (int ks = 0; ks < 2; ++ks) {
      short8 af[2], bfr[4];
#pragma unroll
      for (int i = 0; i < 2; ++i)
        af[i] = *(const short8*)(As + ks * 2048 + (wr * 32 + i * 16 + ln) * 32 + swz);
#pragma unroll
      for (int j = 0; j < 4; ++j)
        bfr[j] = *(const short8*)(Bs + ks * 4096 + (wc * 64 + j * 16 + ln) * 32 + swz);
#pragma unroll
      for (int i = 0; i < 2; ++i)
#pragma unroll
        for (int j = 0; j < 4; ++j)
          acc[i][j] = __builtin_amdgcn_mfma_f32_16x16x32_bf16(af[i], bfr[j], acc[i][j], 0, 0, 0);
    }
  }

#pragma unroll
  for (int j = 0; j < 4; ++j) {
    int col = col0 + wc * 64 + j * 16 + ln;
    float bb = bias[col];
#pragma unroll
    for (int i = 0; i < 2; ++i)
#pragma unroll
      for (int r = 0; r < 4; ++r) {
        int row = row0 + wr * 32 + i * 16 + quad * 4 + r;
        out[(size_t)row * DM + col] = acc[i][j][r] + bb;
      }
  }
}

// ----------------------------------------------- flash attention, KV-split --
// 64-row q-tiles, 4 waves x 16 q-rows, CH=2 strided chunks (round-5 shape,
// 25.6 KB LDS -> ~6 blocks/CU) + XOR swizzle (round-6 conflict fix).
// S^T = K*Q^T; P truncation-packed; empty (qt=0,ch=1) block zero-fills.
__global__ __launch_bounds__(256) void attn_partial(
    const short* __restrict__ Q, const short* __restrict__ Kc,
    const short* __restrict__ Vtg, short* __restrict__ Po,
    float* __restrict__ Lo) {
  const int tid = threadIdx.x;
  const int lane = tid & 63;
  const int w = tid >> 6;       // 0..3
  const int quad = lane >> 4;
  const int ln = lane & 15;
  const int swz = (quad ^ ((ln >> 1) & 3)) * 8;
  const int bh = blockIdx.y;
  const int bx = blockIdx.x;    // 0..63
  const int qt = 31 - (bx >> 1);  // longest first
  const int ch = bx & (CH - 1);
  const size_t idx = ((size_t)bh * 32 + qt) * CH + ch;

  if (ch > qt) {  // empty chunk: zero partials so fused consumer reads blind
    short8 z = (short8){0, 0, 0, 0, 0, 0, 0, 0};
    short8* Pz = (short8*)(Po + idx * 4096);
    Pz[tid] = z;
    Pz[256 + tid] = z;
    if (tid < 64) Lo[idx * 64 + tid] = 0.f;
    return;
  }

  const int q0 = qt * 64;
  const int wlo = q0 + w * 16;

  const short* Qb = Q + (size_t)bh * SEQ * HD;
  const short* Kb = Kc + (size_t)bh * SEQ * HD;
  const short* Vb = Vtg + (size_t)bh * HD * SEQ;

  __shared__ __align__(16) short Ks[2 * 64 * 32];  // [kk(d-half)][s'][32] swz
  __shared__ __align__(16) short Vs[2 * 64 * 32];  // [kk(s'-half)][d][32] swz
  __shared__ __align__(16) short Pt[4][16 * 72];   // per-wave P^T round-trip

  short8 qa[2];
#pragma unroll
  for (int kk = 0; kk < 2; ++kk)
    qa[kk] = *(const short8*)(Qb + (size_t)(wlo + ln) * HD + quad * 8 + kk * 32);

  floatx4 oacc[4];
  float lp = 0.f;
#pragma unroll
  for (int jd = 0; jd < 4; ++jd) oacc[jd] = (floatx4){0.f, 0.f, 0.f, 0.f};

  for (int t = ch * 64; t <= q0; t += CH * 64) {
    __syncthreads();
#pragma unroll
    for (int g = 0; g < 2; ++g) {
      int slot = (w * 2 + g) * 64 + lane;  // 0..511
      int kk = slot >> 8;
      int rowi = (slot >> 2) & 63;
      int grp = (slot & 3) ^ ((slot >> 3) & 3);
      async_ld16(Kb + (size_t)(t + rowi) * HD + kk * 32 + grp * 8,
                 (char*)Ks + slot * 16);
      async_ld16(Vb + (size_t)rowi * SEQ + t + kk * 32 + grp * 8,
                 (char*)Vs + slot * 16);
    }
    __syncthreads();

    // S^T = K * Q^T
    floatx4 sacc[4];
#pragma unroll
    for (int c = 0; c < 4; ++c) sacc[c] = (floatx4){0.f, 0.f, 0.f, 0.f};
#pragma unroll
    for (int kk = 0; kk < 2; ++kk)
#pragma unroll
      for (int c = 0; c < 4; ++c) {
        short8 kb = *(const short8*)(Ks + kk * 2048 + (c * 16 + ln) * 32 + swz);
        sacc[c] = __builtin_amdgcn_mfma_f32_16x16x32_bf16(kb, qa[kk], sacc[c], 0, 0, 0);
      }

    // exp (no max), mask diag tile, truncating bf16 pack via v_perm
    const bool dmask = (t == q0);
#pragma unroll
    for (int c = 0; c < 4; ++c) {
      float p[4];
#pragma unroll
      for (int r = 0; r < 4; ++r) {
        float pv = __expf(sacc[c][r]);
        if (dmask) {
          int sp = t + c * 16 + quad * 4 + r;
          int qq = wlo + ln;
          if (sp > qq) pv = 0.f;
        }
        lp += pv;
        p[r] = pv;
      }
      uint2 uu;
      uu.x = pktrunc(p[0], p[1]);
      uu.y = pktrunc(p[2], p[3]);
      *(uint2*)(&Pt[w][ln * 72 + c * 16 + quad * 4]) = uu;
    }
    // Pt wave-private; lgkmcnt orders write->read

    // O^T += V^T * P^T
#pragma unroll
    for (int kk = 0; kk < 2; ++kk) {
      short8 pb = *(const short8*)(&Pt[w][ln * 72 + kk * 32 + quad * 8]);
#pragma unroll
      for (int jd = 0; jd < 4; ++jd) {
        short8 va = *(const short8*)(Vs + kk * 2048 + (jd * 16 + ln) * 32 + swz);
        oacc[jd] = __builtin_amdgcn_mfma_f32_16x16x32_bf16(va, pb, oacc[jd], 0, 0, 0);
      }
    }
  }

  // store partials: O^T C-layout lane=q(ln), d=jd*16+quad*4+r
  short* Pob = Po + idx * 4096;
#pragma unroll
  for (int jd = 0; jd < 4; ++jd) {
    short4v pk;
#pragma unroll
    for (int r = 0; r < 4; ++r) pk[r] = f2bf(oacc[jd][r]);
    *(short4v*)(Pob + (w * 16 + ln) * 64 + jd * 16 + quad * 4) = pk;
  }
  float l = lp;
  l += __shfl_xor(l, 16, 64);
  l += __shfl_xor(l, 32, 64);
  if (quad == 0) Lo[idx * 64 + w * 16 + ln] = l;
}

// ------------------------------------------------------------------ launch --
extern "C" void kernel_launch(void* const* d_in, const int* in_sizes, int n_in,
                              void* d_out, int out_size, void* d_ws, size_t ws_size,
                              hipStream_t stream) {
  const float* qx  = (const float*)d_in[0];
  const float* kvx = (const float*)d_in[1];
  const float* Wq = (const float*)d_in[4];
  const float* bq = (const float*)d_in[5];
  const float* Wk = (const float*)d_in[6];
  const float* Wv = (const float*)d_in[7];
  const float* bv = (const float*)d_in[8];
  const float* Wo = (const float*)d_in[9];
  const float* bo = (const float*)d_in[10];
  const int* qpos  = (const int*)d_in[11];
  const int* kvpos = (const int*)d_in[12];

  char* ws = (char*)d_ws;
  short* qxb  = (short*)(ws + 0);
  short* kvxb = (short*)(ws + 8388608);
  short* Wqb  = (short*)(ws + 16777216);
  short* Wkb  = (short*)(ws + 18874368);
  short* Wvb  = (short*)(ws + 20971520);
  short* Wob  = (short*)(ws + 23068672);
  short* Qbf  = (short*)(ws + 25165824);
  short* Kbf  = (short*)(ws + 33554432);
  short* Vtb  = (short*)(ws + 41943040);
  float2* qtab = (float2*)(ws + 50331648);
  float2* ktab = (float2*)(ws + 50331648 + 524288);
  short* Po = (short*)(ws + 0);          // 32*32*CH*4096 bf16 = 16 MB
  float* Lo = (float*)(ws + 16777216);   // 32*32*CH*64 fp32 = 512 KB

  Cvt8 c;
  c.src[0] = qx;  c.dst[0] = qxb;  c.n[0] = MROWS * KDIM; c.pos[0] = nullptr;
  c.src[1] = kvx; c.dst[1] = kvxb; c.n[1] = MROWS * KDIM; c.pos[1] = nullptr;
  c.src[2] = Wq;  c.dst[2] = Wqb;  c.n[2] = DM * KDIM;    c.pos[2] = nullptr;
  c.src[3] = Wk;  c.dst[3] = Wkb;  c.n[3] = DM * KDIM;    c.pos[3] = nullptr;
  c.src[4] = Wv;  c.dst[4] = Wvb;  c.n[4] = DM * KDIM;    c.pos[4] = nullptr;
  c.src[5] = Wo;  c.dst[5] = Wob;  c.n[5] = DM * KDIM;    c.pos[5] = nullptr;
  c.src[6] = nullptr; c.dst[6] = qtab; c.n[6] = SEQ * 32; c.pos[6] = qpos;
  c.src[7] = nullptr; c.dst[7] = ktab; c.n[7] = SEQ * 32; c.pos[7] = kvpos;
  convert8<<<dim3(1024, 8), 256, 0, stream>>>(c);

  proj_gemm<<<dim3(DM / 128, MROWS / 128, 3), 256, 0, stream>>>(
      qxb, kvxb, Wqb, Wkb, Wvb, bq, bv, Qbf, Kbf, Vtb, qtab, ktab);

  attn_partial<<<dim3(32 * CH, 2 * NH), 256, 0, stream>>>(Qbf, Kbf, Vtb, Po, Lo);

  out_gemm<<<dim3(64 * 8), 256, 0, stream>>>(Po, Lo, Wob, bo, (float*)d_out);
}